// Round 4
// baseline (612.742 us; speedup 1.0000x reference)
//
#include <hip/hip_runtime.h>
#include <hip/hip_bf16.h>
#include <stdint.h>

// Problem constants (fixed by the reference)
#define N_ 16384
#define M_ 4096
#define D_ 256
#define O_ 256

// Workspace layout (bytes)
#define WS_T     0              // float[N]      exp(sf+ba)           64 KB
#define WS_U     65536          // float[M]      exp(sc)              16 KB
#define WS_R     81920          // float[D]      colsum(Hc)            1 KB
#define WS_LSUM  98304          // float[N]      softmax denom sums   64 KB
#define WS_WTP   163840         // ushort[8*16*64*8]  Wt packed      128 KB
#define WS_BP    294912         // ushort[128*16*64*8] Hc packed       2 MB
#define WS_C     4194304        // float[N*D]    partial C            16 MB

typedef float  f32x4  __attribute__((ext_vector_type(4)));
typedef short  short8 __attribute__((ext_vector_type(8)));

// fp32 -> bf16 (RNE). Inputs are finite so no NaN handling.
__device__ __forceinline__ unsigned short f2bf(float f) {
  uint32_t u = __float_as_uint(f);
  u += 0x7FFFu + ((u >> 16) & 1u);
  return (unsigned short)(u >> 16);
}

// ---------------------------------------------------------------------------
// Prep 1: per-row dot with weight vector, then exp(dot + bias).
__global__ __launch_bounds__(256) void rowdot_exp_kernel(
    const float* __restrict__ X, const float* __restrict__ w,
    const float* __restrict__ bias, float* __restrict__ outv) {
  int wv = threadIdx.x >> 6, lane = threadIdx.x & 63;
  int row = blockIdx.x * 4 + wv;
  const float4* x4 = (const float4*)(X + (size_t)row * D_);
  const float4* w4 = (const float4*)w;
  float4 xa = x4[lane], wa4 = w4[lane];
  float s = xa.x * wa4.x + xa.y * wa4.y + xa.z * wa4.z + xa.w * wa4.w;
#pragma unroll
  for (int off = 32; off > 0; off >>= 1) s += __shfl_xor(s, off);
  if (lane == 0) outv[row] = expf(s + (bias ? bias[0] : 0.0f));
}

// ---------------------------------------------------------------------------
// Prep 2: Hc [M,D] fp32 -> BP fragment-major bf16 + R = colsum(Hc).
// BP[((kg*16 + cg)*64 + lane)*8 + j] = bf16(Hc[kg*32+q*8+j][cg*16+m]),
// lane = q*16+m  (the exact MFMA B-fragment; loads become base+lane*16B).
__global__ __launch_bounds__(256) void hc_pack_kernel(
    const float* __restrict__ Hc, unsigned short* __restrict__ BP,
    float* __restrict__ R) {
  __shared__ float tile[64][65];
  __shared__ float red[4][64];
  int bk = blockIdx.x >> 2;   // 64 tiles along M (k)
  int bc = blockIdx.x & 3;    // 4 tiles along D (col)
  int k0 = bk * 64, col0 = bc * 64;
  int t = threadIdx.x;
  int lane = t & 63, wv = t >> 6;
  int m = lane & 15, q = lane >> 4;
  float colsum = 0.0f;
#pragma unroll
  for (int i = 0; i < 16; ++i) {
    int e = t + 256 * i;
    int kk = e >> 6, cc = e & 63;
    float v = Hc[(size_t)(k0 + kk) * D_ + col0 + cc];
    tile[kk][cc] = v;
    colsum += v;
  }
  red[wv][t & 63] = colsum;
  __syncthreads();
  if (t < 64)
    atomicAdd(&R[col0 + t], red[0][t] + red[1][t] + red[2][t] + red[3][t]);
#pragma unroll
  for (int t8 = 0; t8 < 2; ++t8) {
    int tile_id = t8 * 4 + wv;
    int sub = tile_id >> 2, g = tile_id & 3;
    int kgg = bk * 2 + sub;
    int cgg = bc * 4 + g;
    short8 v8;
#pragma unroll
    for (int j = 0; j < 8; ++j)
      v8[j] = (short)f2bf(tile[sub * 32 + q * 8 + j][g * 16 + m]);
    *(short8*)(BP + ((size_t)(kgg * 16 + cgg) * 64 + lane) * 8) = v8;
  }
}

// ---------------------------------------------------------------------------
// Prep 3: Wt [O,D] fp32 -> WtP fragment-major bf16 (kg 0..7, cg 0..15).
__global__ __launch_bounds__(256) void wt_pack_kernel(
    const float* __restrict__ Wt, unsigned short* __restrict__ WtP) {
  int t = blockIdx.x * 256 + threadIdx.x;    // 0..8191
  int lane = t & 63, cg = (t >> 6) & 15, kg = t >> 10;
  int m = lane & 15, q = lane >> 4;
  const float* src = Wt + (size_t)(cg * 16 + m) * D_ + kg * 32 + q * 8;
  float4 w0 = *(const float4*)src, w1 = *(const float4*)(src + 4);
  short8 v8;
  v8[0] = (short)f2bf(w0.x); v8[1] = (short)f2bf(w0.y);
  v8[2] = (short)f2bf(w0.z); v8[3] = (short)f2bf(w0.w);
  v8[4] = (short)f2bf(w1.x); v8[5] = (short)f2bf(w1.y);
  v8[6] = (short)f2bf(w1.z); v8[7] = (short)f2bf(w1.w);
  *(short8*)(WtP + (size_t)t * 8) = v8;
}

// ---------------------------------------------------------------------------
// Main split-K kernel (barrier-free K loop):
//   A'_ij = adj_ij*(t_i*u_j - 1) built fragment-direct in registers;
//   B fragments register-loaded from prepacked BP (L2-resident);
//   each wave: 32 rows (2 rtiles sharing B frags) x 64 cols, K-half = 2048.
//   Partial C -> fp32 atomicAdd; partial softmax denom -> atomicAdd.
// Grid = (N/32)*2 = 1024 blocks of 256 thr -> 4 blocks/CU = 16 waves/CU.
// Depth-1 double-set register prefetch; only LDS use is a read-only u table.
__global__ __launch_bounds__(256, 4) void main_split_kernel(
    const float* __restrict__ adj, const unsigned short* __restrict__ BP,
    const float* __restrict__ tv, const float* __restrict__ uv,
    float* __restrict__ Cbuf, float* __restrict__ Lsum) {
  __shared__ float u_lds[2048];
  int tid = threadIdx.x;
  int w = tid >> 6, lane = tid & 63;
  int q = lane >> 4, m = lane & 15;
  int kh = blockIdx.x & 1, rb = blockIdx.x >> 1;
  int i0 = rb * 32;
  int c0 = w * 64;

  for (int i = tid; i < 2048; i += 256) u_lds[i] = uv[kh * 2048 + i];

  float t0 = tv[i0 + m], t1 = tv[i0 + 16 + m];
  const float* ar0 = adj + (size_t)(i0 + m) * M_ + kh * 2048 + q * 8;
  const float* ar1 = ar0 + (size_t)16 * M_;
  const unsigned short* bb = BP + (size_t)(kh * 64 * 16 + w * 4) * 512 + (size_t)lane * 8;

  f32x4 acc[2][4];
#pragma unroll
  for (int r = 0; r < 2; ++r)
#pragma unroll
    for (int n = 0; n < 4; ++n) acc[r][n] = (f32x4){0.f, 0.f, 0.f, 0.f};
  float rs0 = 0.0f, rs1 = 0.0f;

  __syncthreads();  // u_lds ready (only barrier in the kernel)

  // set X = even iters, set Y = odd iters (register double-buffer)
  float4 aX00 = *(const float4*)ar0, aX01 = *(const float4*)(ar0 + 4);
  float4 aX10 = *(const float4*)ar1, aX11 = *(const float4*)(ar1 + 4);
  short8 bX[4], bY[4];
#pragma unroll
  for (int n = 0; n < 4; ++n) bX[n] = *(const short8*)(bb + n * 512);
  float4 aY00, aY01, aY10, aY11;

#define XF(A0, A1, TR, U0, U1, RS, AF)                                  \
  {                                                                     \
    float ax[8] = {A0.x, A0.y, A0.z, A0.w, A1.x, A1.y, A1.z, A1.w};     \
    float ux[8] = {U0.x, U0.y, U0.z, U0.w, U1.x, U1.y, U1.z, U1.w};     \
    _Pragma("unroll") for (int j = 0; j < 8; ++j) {                     \
      float p = fmaf(ax[j], TR * ux[j], -ax[j]);                        \
      RS += p;                                                          \
      AF[j] = (short)f2bf(p);                                           \
    }                                                                   \
  }

  for (int kk = 0; kk < 64; kk += 2) {
    // prefetch odd iter kk+1 into set Y
    {
      const float* p0 = ar0 + (kk + 1) * 32;
      const float* p1 = ar1 + (kk + 1) * 32;
      aY00 = *(const float4*)p0; aY01 = *(const float4*)(p0 + 4);
      aY10 = *(const float4*)p1; aY11 = *(const float4*)(p1 + 4);
      const unsigned short* bp = bb + (size_t)(kk + 1) * 8192;
#pragma unroll
      for (int n = 0; n < 4; ++n) bY[n] = *(const short8*)(bp + n * 512);
    }
    // consume even iter kk (set X)
    {
      float4 u0 = *(const float4*)&u_lds[kk * 32 + q * 8];
      float4 u1 = *(const float4*)&u_lds[kk * 32 + q * 8 + 4];
      short8 af0, af1;
      XF(aX00, aX01, t0, u0, u1, rs0, af0);
      XF(aX10, aX11, t1, u0, u1, rs1, af1);
#pragma unroll
      for (int n = 0; n < 4; ++n) {
        acc[0][n] = __builtin_amdgcn_mfma_f32_16x16x32_bf16(af0, bX[n], acc[0][n], 0, 0, 0);
        acc[1][n] = __builtin_amdgcn_mfma_f32_16x16x32_bf16(af1, bX[n], acc[1][n], 0, 0, 0);
      }
    }
    // prefetch even iter kk+2 into set X (wrap at end: harmless reload of 0)
    {
      int k2 = (kk + 2) & 63;
      const float* p0 = ar0 + k2 * 32;
      const float* p1 = ar1 + k2 * 32;
      aX00 = *(const float4*)p0; aX01 = *(const float4*)(p0 + 4);
      aX10 = *(const float4*)p1; aX11 = *(const float4*)(p1 + 4);
      const unsigned short* bp = bb + (size_t)k2 * 8192;
#pragma unroll
      for (int n = 0; n < 4; ++n) bX[n] = *(const short8*)(bp + n * 512);
    }
    // consume odd iter kk+1 (set Y)
    {
      float4 u0 = *(const float4*)&u_lds[(kk + 1) * 32 + q * 8];
      float4 u1 = *(const float4*)&u_lds[(kk + 1) * 32 + q * 8 + 4];
      short8 af0, af1;
      XF(aY00, aY01, t0, u0, u1, rs0, af0);
      XF(aY10, aY11, t1, u0, u1, rs1, af1);
#pragma unroll
      for (int n = 0; n < 4; ++n) {
        acc[0][n] = __builtin_amdgcn_mfma_f32_16x16x32_bf16(af0, bY[n], acc[0][n], 0, 0, 0);
        acc[1][n] = __builtin_amdgcn_mfma_f32_16x16x32_bf16(af1, bY[n], acc[1][n], 0, 0, 0);
      }
    }
  }
#undef XF

  // partial softmax denominators: reduce across the 4 k-quads, one add per row
  rs0 += __shfl_xor(rs0, 16); rs0 += __shfl_xor(rs0, 32);
  rs1 += __shfl_xor(rs1, 16); rs1 += __shfl_xor(rs1, 32);
  if (w == 0 && lane < 16) {
    atomicAdd(&Lsum[i0 + m], rs0);
    atomicAdd(&Lsum[i0 + 16 + m], rs1);
  }

  // partial C accumulation (each address hit by exactly 2 blocks)
#pragma unroll
  for (int r = 0; r < 2; ++r)
#pragma unroll
    for (int n = 0; n < 4; ++n) {
      int col = c0 + n * 16 + m;
#pragma unroll
      for (int j = 0; j < 4; ++j) {
        int row = i0 + r * 16 + q * 4 + j;   // C/D: row=(lane>>4)*4+reg
        atomicAdd(&Cbuf[(size_t)row * D_ + col], acc[r][n][j]);
      }
    }
}

// ---------------------------------------------------------------------------
// Epilogue: attn = (C + R)/(Lsum + M) + Hf  -> LDS bf16 -> out = relu(attn@Wt^T+bt)
__global__ __launch_bounds__(256, 4) void epilogue_kernel(
    const float* __restrict__ Cbuf, const float* __restrict__ Lsum,
    const float* __restrict__ Rv, const float* __restrict__ Hf,
    const unsigned short* __restrict__ WtP, const float* __restrict__ bt,
    float* __restrict__ out) {
  __shared__ alignas(16) unsigned short attn[32][264];  // +8 pad
  int tid = threadIdx.x;
  int w = tid >> 6, lane = tid & 63;
  int rtile = w & 1, chalf = w >> 1;
  int q = lane >> 4, m = lane & 15;
  int i0 = blockIdx.x * 32;

  float4 rv = *(const float4*)(Rv + lane * 4);
#pragma unroll
  for (int rr = 0; rr < 8; ++rr) {
    int r = w * 8 + rr;                       // wave w owns rows w*8..w*8+7
    float invL = 1.0f / (Lsum[i0 + r] + (float)M_);
    float4 cv = *(const float4*)(Cbuf + (size_t)(i0 + r) * D_ + lane * 4);
    float4 hv = *(const float4*)(Hf + (size_t)(i0 + r) * D_ + lane * 4);
    attn[r][lane * 4 + 0] = f2bf(fmaf(cv.x + rv.x, invL, hv.x));
    attn[r][lane * 4 + 1] = f2bf(fmaf(cv.y + rv.y, invL, hv.y));
    attn[r][lane * 4 + 2] = f2bf(fmaf(cv.z + rv.z, invL, hv.z));
    attn[r][lane * 4 + 3] = f2bf(fmaf(cv.w + rv.w, invL, hv.w));
  }
  __syncthreads();

  f32x4 facc[8];
#pragma unroll
  for (int n = 0; n < 8; ++n) facc[n] = (f32x4){0.f, 0.f, 0.f, 0.f};
  const unsigned short* wwave = WtP + (size_t)chalf * 4096 + (size_t)lane * 8;
#pragma unroll
  for (int kf = 0; kf < 8; ++kf) {
    short8 af = *(const short8*)&attn[rtile * 16 + m][kf * 32 + q * 8];
#pragma unroll
    for (int n = 0; n < 8; ++n) {
      short8 bf = *(const short8*)(wwave + ((size_t)kf * 16 + n) * 512);
      facc[n] = __builtin_amdgcn_mfma_f32_16x16x32_bf16(af, bf, facc[n], 0, 0, 0);
    }
  }
#pragma unroll
  for (int n = 0; n < 8; ++n) {
    int col = chalf * 128 + n * 16 + m;
    float b = bt[col];
#pragma unroll
    for (int r = 0; r < 4; ++r) {
      size_t row = (size_t)i0 + rtile * 16 + q * 4 + r;
      out[row * O_ + col] = fmaxf(facc[n][r] + b, 0.0f);
    }
  }
}

// ---------------------------------------------------------------------------
extern "C" void kernel_launch(void* const* d_in, const int* in_sizes, int n_in,
                              void* d_out, int out_size, void* d_ws, size_t ws_size,
                              hipStream_t stream) {
  const float* Hf  = (const float*)d_in[0];  // [N,D]
  const float* Hc  = (const float*)d_in[1];  // [M,D]
  const float* adj = (const float*)d_in[2];  // [N,M]
  const float* wa  = (const float*)d_in[3];  // [2D]
  const float* ba  = (const float*)d_in[4];  // [1]
  const float* Wt  = (const float*)d_in[5];  // [O,D]
  const float* bt  = (const float*)d_in[6];  // [O]
  float* out = (float*)d_out;

  char* ws = (char*)d_ws;
  float* tv   = (float*)(ws + WS_T);
  float* uv   = (float*)(ws + WS_U);
  float* Rv   = (float*)(ws + WS_R);
  float* Lsum = (float*)(ws + WS_LSUM);
  unsigned short* WtP = (unsigned short*)(ws + WS_WTP);
  unsigned short* BP  = (unsigned short*)(ws + WS_BP);
  float* Cbuf = (float*)(ws + WS_C);

  hipMemsetAsync(Rv, 0, D_ * sizeof(float), stream);
  hipMemsetAsync(Lsum, 0, N_ * sizeof(float), stream);
  hipMemsetAsync(Cbuf, 0, (size_t)N_ * D_ * sizeof(float), stream);

  rowdot_exp_kernel<<<N_ / 4, 256, 0, stream>>>(Hf, wa, ba, tv);           // t = exp(sf+ba)
  rowdot_exp_kernel<<<M_ / 4, 256, 0, stream>>>(Hc, wa + D_, nullptr, uv); // u = exp(sc)
  hc_pack_kernel<<<256, 256, 0, stream>>>(Hc, BP, Rv);
  wt_pack_kernel<<<32, 256, 0, stream>>>(Wt, WtP);

  main_split_kernel<<<N_ / 32 * 2, 256, 0, stream>>>(adj, BP, tv, uv, Cbuf, Lsum);
  epilogue_kernel<<<N_ / 32, 256, 0, stream>>>(Cbuf, Lsum, Rv, Hf, WtP, bt, out);
}